// Round 9
// baseline (117.650 us; speedup 1.0000x reference)
//
#include <hip/hip_runtime.h>
#include <hip/hip_bf16.h>
#include <math.h>

// S5 SSM layer. B_SZ=16, L=1024, H=256, P=256.
// R19: k_prep -> k_main. B operands (W1/W2, L2-resident) now DIRECT-TO-REGISTER
// with explicit 3/4-slot static rotation (full unroll; rule-#20-safe), giving each
// load a 2-3 k-step window. No LDS B, no staging barriers, no manual vmcnt —
// compiler's per-register waitcnt handles sync. A (u) stays in swizzled LDS;
// X/scan/prefix/fixup unchanged from R18.
#define BB     16
#define LSEQ   1024
#define HH     256
#define PP     256
#define LC     32
#define NC     (LSEQ/LC)     // 32
#define NCHUNK (BB*NC)       // 512

// workspace byte offsets
#define OFF_W1T  0u          // [512][256] bf16: row 2p=Re(B_bar[p][.]), 2p+1=Im
#define OFF_W2T  262144u     // [256][512] bf16: row h, k=2p -> 2*C_re, 2p+1 -> -2*C_im
#define OFF_PW   524288u     // [33][256] float2: lambda_bar^t
#define OFF_CEND 655360u     // [512][256] float2 chunk-end local states (1 MB)
#define OFF_BAR  2752512u    // batch-barrier area (zeroed by k_prep block 0)

typedef __attribute__((ext_vector_type(8))) short short8;
typedef __attribute__((ext_vector_type(4))) float floatx4;
typedef unsigned long long ull;

__device__ __forceinline__ float bf2f(unsigned hs) {
    union { unsigned u; float f; } v; v.u = hs << 16; return v.f;
}
__device__ __forceinline__ unsigned short f2bs(float f) {
    __hip_bfloat16 h = __float2bfloat16(f);
    union { __hip_bfloat16 h; unsigned short s; } v; v.h = h; return v.s;
}
__device__ __forceinline__ unsigned packbf(float r, float i) {
    return (unsigned)f2bs(r) | ((unsigned)f2bs(i) << 16);
}
__device__ __forceinline__ float2 lam_pow(float lr, float li, float dtt) {
    float m = expf(lr * dtt);
    return make_float2(m * cosf(li * dtt), m * sinf(li * dtt));
}
__device__ __forceinline__ void cohst64(ull* p, float2 v) {
    ull b; __builtin_memcpy(&b, &v, 8);
    __hip_atomic_store(p, b, __ATOMIC_RELAXED, __HIP_MEMORY_SCOPE_AGENT);
}

// Batch-scope barrier: 32 blocks of one batch (bc>>5). No cache fences —
// CEND uses sc1 stores (coherent at L3); vmcnt(0) drains them pre-arrival.
__device__ __forceinline__ void batchbar(char* base) {
    asm volatile("s_waitcnt vmcnt(0)" ::: "memory");
    __syncthreads();
    if (threadIdx.x == 0) {
        const unsigned b = blockIdx.x >> 5;
        unsigned* cnt  = (unsigned*)(base + b * 64);
        unsigned* flag = (unsigned*)(base + 2048 + b * 64);
        if (__hip_atomic_fetch_add(cnt, 1u, __ATOMIC_RELAXED,
                                   __HIP_MEMORY_SCOPE_AGENT) == 31u) {
            __hip_atomic_store(flag, 1u, __ATOMIC_RELAXED, __HIP_MEMORY_SCOPE_AGENT);
        } else {
            for (int it = 0; it < (1 << 18); ++it) {   // bounded: no hang
                if (__hip_atomic_load(flag, __ATOMIC_RELAXED, __HIP_MEMORY_SCOPE_AGENT))
                    break;
                __builtin_amdgcn_s_sleep(2);
            }
        }
    }
    __syncthreads();
}

// ---------------- k_prep: W1T/PW (blocks 0..255), W2T (256..511), bar init ------
__global__ void k_prep(const float* __restrict__ Bm, const float* __restrict__ Cm,
                       const float* __restrict__ Lr, const float* __restrict__ Li,
                       const float* __restrict__ ls, char* __restrict__ ws) {
    int blk = blockIdx.x, t = threadIdx.x;
    if (blk < 256) {
        if (t < 128) {
            int p = blk;
            float lr = Lr[p], li = Li[p];
            float dt = expf(ls[p]);
            float2 lam = lam_pow(lr, li, dt);
            float den = lr * lr + li * li;
            float nr = lam.x - 1.0f, ni = lam.y;
            float cr = (nr * lr + ni * li) / den;    // (lam_bar-1)/Lambda
            float ci = (ni * lr - nr * li) / den;
            float4 bv = *(const float4*)(Bm + (size_t)p * 512 + 4 * t);
            unsigned* w1u = (unsigned*)(ws + OFF_W1T);
            w1u[(2 * p) * 128 + t]     = packbf(cr * bv.x - ci * bv.y, cr * bv.z - ci * bv.w);
            w1u[(2 * p + 1) * 128 + t] = packbf(cr * bv.y + ci * bv.x, cr * bv.w + ci * bv.z);
            if (t <= 32)
                ((float2*)(ws + OFF_PW))[t * 256 + p] = lam_pow(lr, li, dt * (float)t);
        }
        if (blk == 0)   // zero batch-barrier area (4 KB)
            ((float4*)(ws + OFF_BAR))[t] = make_float4(0.f, 0.f, 0.f, 0.f);
    } else {
        int h = blk - 256, p = t;
        float c_r = Cm[(h * PP + p) * 2 + 0];
        float c_i = Cm[(h * PP + p) * 2 + 1];
        ((unsigned*)(ws + OFF_W2T))[h * 256 + p] = packbf(2.0f * c_r, -2.0f * c_i);
    }
}

// LDS map (35328 B, fits 4 blocks/CU; grid runs 2/CU):
//   GEMM1 : A  @0      [32 rows][512 B] bf16, k-byte XOR-swizzled by (row&7)<<4
//   later : X  @0      [32][520] bf16 (33280 B)
//           carrs @33280 [256] float2 (2 KB)
#define XSTRS 520
#define XSTRD 260
#define CARR_OFF 33280

#define MFMA16(a, b, c) __builtin_amdgcn_mfma_f32_16x16x32_bf16((a), (b), (c), 0, 0, 0)

__global__ __launch_bounds__(512, 4) void k_main(
        const float* __restrict__ u, const float* __restrict__ Lr,
        const float* __restrict__ Li, const float* __restrict__ ls,
        const float* __restrict__ D, float* __restrict__ out,
        char* __restrict__ ws) {
    extern __shared__ char smem[];
    const int tid = threadIdx.x, bc = blockIdx.x;
    const int wave = tid >> 6, lane = tid & 63;
    const int q = lane >> 4, rr = lane & 15;
    const int m0 = bc * LC;

    // ---- u tile preload (issued first) ------------------------------------------
    const int arow = tid >> 4, acol = (tid & 15) * 16;   // 16 f32 elems/thread
    float4 uv[4];
    {
        const float* up = u + (size_t)(m0 + arow) * 256 + acol;
        #pragma unroll
        for (int i = 0; i < 4; ++i) uv[i] = *(const float4*)(up + 4 * i);
    }

    // ---- GEMM1 B prologue: slots t=0,1,2 direct to registers (window: u-pack) ---
    const char* W1 = (const char*)(ws + OFF_W1T);
    const char* W1w = W1 + (size_t)(wave * 64 + rr) * 512 + q * 16;  // j stride 16*512
    short8 b0[4], b1[4], b2[4];
#define LOADB1(slot, t)                                              \
    { _Pragma("unroll")                                              \
      for (int j = 0; j < 4; ++j)                                    \
          slot[j] = *(const short8*)(W1w + j * 8192 + (t) * 64); }
    LOADB1(b0, 0) LOADB1(b1, 1) LOADB1(b2, 2)

    // ---- pack u -> bf16 into swizzled LDS A -------------------------------------
    {
        unsigned pk[8];
        #pragma unroll
        for (int i = 0; i < 4; ++i) {
            pk[2 * i]     = packbf(uv[i].x, uv[i].y);
            pk[2 * i + 1] = packbf(uv[i].z, uv[i].w);
        }
        const int kb = acol * 2;                   // k-byte base (32 B/thread)
        const int msk = (arow & 7) << 4;
        char* A = smem;
        *(uint4*)(A + arow * 512 + (kb ^ msk))        = make_uint4(pk[0], pk[1], pk[2], pk[3]);
        *(uint4*)(A + arow * 512 + ((kb + 16) ^ msk)) = make_uint4(pk[4], pk[5], pk[6], pk[7]);
    }
    __syncthreads();                           // A visible to all waves

    // ---------------- GEMM1 (BM=32, BN=512, K=256), 8 steps, 3-slot rotation -----
    {
        const char* A = smem;
        const int amask = (rr & 7) << 4;
        floatx4 acc[2][4];
        #pragma unroll
        for (int i = 0; i < 2; ++i)
            #pragma unroll
            for (int j = 0; j < 4; ++j) acc[i][j] = (floatx4)0.0f;

#define STEP1(t, slot)                                                        \
    {   const int kbA = (t) * 64 + q * 16;                                    \
        short8 a0 = *(const short8*)(A + rr * 512 + (kbA ^ amask));           \
        short8 a1 = *(const short8*)(A + (16 + rr) * 512 + (kbA ^ amask));    \
        _Pragma("unroll")                                                     \
        for (int j = 0; j < 4; ++j) {                                         \
            acc[0][j] = MFMA16(a0, slot[j], acc[0][j]);                       \
            acc[1][j] = MFMA16(a1, slot[j], acc[1][j]);                       \
        } }
        STEP1(0, b0) LOADB1(b0, 3)
        STEP1(1, b1) LOADB1(b1, 4)
        STEP1(2, b2) LOADB1(b2, 5)
        STEP1(3, b0) LOADB1(b0, 6)
        STEP1(4, b1) LOADB1(b1, 7)
        STEP1(5, b2)
        STEP1(6, b0)
        STEP1(7, b1)
#undef STEP1
#undef LOADB1
        __syncthreads();                       // all waves done with A
        // dump Bu tile (32 x 512) into padded LDS X (overwrites A)
        unsigned short* X = (unsigned short*)smem;
        #pragma unroll
        for (int i = 0; i < 2; ++i)
            #pragma unroll
            for (int j = 0; j < 4; ++j)
                #pragma unroll
                for (int r0 = 0; r0 < 4; ++r0)
                    X[(i * 16 + q * 4 + r0) * XSTRS + wave * 64 + j * 16 + rr] =
                        f2bs(acc[i][j][r0]);
        __syncthreads();
    }

    // ---------------- local scan (waves 0-3; 256 channel pairs) ------------------
    if (tid < 256) {
        const int pq = tid;
        const float2 lam = lam_pow(Lr[pq], Li[pq], expf(ls[pq]));
        unsigned* X32 = (unsigned*)smem;
        float xr = 0.0f, xi = 0.0f;
        #pragma unroll
        for (int j = 0; j < LC; ++j) {
            unsigned cv = X32[j * XSTRD + pq];
            float br = bf2f(cv & 0xffffu), bi = bf2f(cv >> 16);
            float nr = fmaf(lam.x, xr, fmaf(-lam.y, xi, br));
            float ni = fmaf(lam.x, xi, fmaf(lam.y, xr, bi));
            xr = nr; xi = ni;
            X32[j * XSTRD + pq] = packbf(xr, xi);   // x_local in place
        }
        cohst64((ull*)(ws + OFF_CEND) + (size_t)bc * 256 + pq, make_float2(xr, xi));
    }
    batchbar(ws + OFF_BAR);        // this batch's CEND at coherent point

    // ---- GEMM2 B prologue: slots t=0..3 direct to registers (window: prefix) ----
    const char* W2 = (const char*)(ws + OFF_W2T);
    const char* W2w = W2 + (size_t)(wave * 32 + rr) * 1024 + q * 16; // j stride 16*1024
    short8 c0[2], c1[2], c2[2], c3[2];
#define LOADB2(slot, t)                                              \
    { _Pragma("unroll")                                              \
      for (int j = 0; j < 2; ++j)                                    \
          slot[j] = *(const short8*)(W2w + j * 16384 + (t) * 64); }
    LOADB2(c0, 0) LOADB2(c1, 1) LOADB2(c2, 2) LOADB2(c3, 3)

    // ---------------- per-block carry via fixed-31 predicated prefix -------------
    {
        float2* carrs = (float2*)(smem + CARR_OFF);
        if (tid < 256) {
            const int p = tid;
            const int c = bc & (NC - 1);
            const int b0i = bc & ~(NC - 1);
            const float2* cend = (const float2*)(ws + OFF_CEND);
            const float2 g = lam_pow(Lr[p], Li[p], expf(ls[p]) * (float)LC);
            float sr = 0.0f, si = 0.0f;
            float gpr = 1.0f, gpi = 0.0f;
            #pragma unroll
            for (int k = 0; k < NC - 1; ++k) {
                int idx = c - 1 - k; idx = idx < 0 ? 0 : idx;
                float2 e = cend[(size_t)(b0i + idx) * 256 + p];
                float er = (k < c) ? e.x : 0.0f;
                float ei = (k < c) ? e.y : 0.0f;
                sr = fmaf(gpr, er, fmaf(-gpi, ei, sr));
                si = fmaf(gpr, ei, fmaf(gpi, er, si));
                float t2 = gpr * g.x - gpi * g.y;
                gpi = gpr * g.y + gpi * g.x; gpr = t2;
            }
            carrs[p] = make_float2(sr, si);
        }
        __syncthreads();
    }

    // ---------------- fixup X in place -------------------------------------------
    {
        float2* carrs = (float2*)(smem + CARR_OFF);
        unsigned* X32 = (unsigned*)smem;
        const float2* pw = (const float2*)(ws + OFF_PW);
        const int frow = tid >> 4, fcol = tid & 15;
        const float2* pwr = pw + (size_t)(frow + 1) * 256;
        #pragma unroll 4
        for (int e = 0; e < 16; ++e) {
            int p = fcol + e * 16;
            unsigned cv = X32[frow * XSTRD + p];
            float2 pwv = pwr[p];
            float2 cav = carrs[p];
            float fr2 = pwv.x * cav.x - pwv.y * cav.y;
            float fi2 = pwv.x * cav.y + pwv.y * cav.x;
            X32[frow * XSTRD + p] =
                packbf(bf2f(cv & 0xffffu) + fr2, bf2f(cv >> 16) + fi2);
        }
        __syncthreads();
    }

    // ---------------- GEMM2 (BM=32, BN=256, K=512), 16 steps, 4-slot rotation ----
    {
        const char* Xb = (const char*)smem;
        floatx4 acc[2][2];
        #pragma unroll
        for (int i = 0; i < 2; ++i)
            #pragma unroll
            for (int j = 0; j < 2; ++j) acc[i][j] = (floatx4)0.0f;

#define STEP2(t, slot)                                                        \
    {   const int kbA = (t) * 64 + q * 16;                                    \
        short8 a0 = *(const short8*)(Xb + rr * (XSTRS * 2) + kbA);            \
        short8 a1 = *(const short8*)(Xb + (16 + rr) * (XSTRS * 2) + kbA);     \
        _Pragma("unroll")                                                     \
        for (int j = 0; j < 2; ++j) {                                         \
            acc[0][j] = MFMA16(a0, slot[j], acc[0][j]);                       \
            acc[1][j] = MFMA16(a1, slot[j], acc[1][j]);                       \
        } }
        STEP2(0,  c0) LOADB2(c0, 4)
        STEP2(1,  c1) LOADB2(c1, 5)
        STEP2(2,  c2) LOADB2(c2, 6)
        STEP2(3,  c3) LOADB2(c3, 7)
        STEP2(4,  c0) LOADB2(c0, 8)
        STEP2(5,  c1) LOADB2(c1, 9)
        STEP2(6,  c2) LOADB2(c2, 10)
        STEP2(7,  c3) LOADB2(c3, 11)
        STEP2(8,  c0) LOADB2(c0, 12)
        STEP2(9,  c1) LOADB2(c1, 13)
        STEP2(10, c2) LOADB2(c2, 14)
        STEP2(11, c3) LOADB2(c3, 15)
        STEP2(12, c0)
        STEP2(13, c1)
        STEP2(14, c2)
        STEP2(15, c3)
#undef STEP2
#undef LOADB2

        #pragma unroll
        for (int i = 0; i < 2; ++i) {
            int mbase = m0 + i * 16 + q * 4;
            #pragma unroll
            for (int j = 0; j < 2; ++j) {
                int col = wave * 32 + j * 16 + rr;
                #pragma unroll
                for (int r0 = 0; r0 < 4; ++r0) {
                    int rw = mbase + r0;
                    size_t gi = (size_t)rw * 256 + col;
                    out[gi] = acc[i][j][r0] + D[col] * u[gi];
                }
            }
        }
    }
}

extern "C" void kernel_launch(void* const* d_in, const int* in_sizes, int n_in,
                              void* d_out, int out_size, void* d_ws, size_t ws_size,
                              hipStream_t stream) {
    const float* u  = (const float*)d_in[0];
    const float* Lr = (const float*)d_in[1];
    const float* Li = (const float*)d_in[2];
    const float* Bm = (const float*)d_in[3];
    const float* Cm = (const float*)d_in[4];
    const float* D  = (const float*)d_in[5];
    const float* ls = (const float*)d_in[6];
    float* out = (float*)d_out;
    char* ws = (char*)d_ws;

    k_prep<<<512, 256, 0, stream>>>(Bm, Cm, Lr, Li, ls, ws);
    k_main<<<NCHUNK, 512, 35328, stream>>>(u, Lr, Li, ls, D, out, ws);
}

// Round 10
// 108.260 us; speedup vs baseline: 1.0867x; 1.0867x over previous
//
#include <hip/hip_runtime.h>
#include <hip/hip_bf16.h>
#include <math.h>

// S5 SSM layer. B_SZ=16, L=1024, H=256, P=256.
// R20 = R18 (best, 104.0us) + staggered carry-ready wait:
//  - per-batch 32-bit readiness bitmask replaces the batch BARRIER. Block with
//    chunk c waits only for bits 0..c-1 (chunk 0 waits for nothing) -> kills the
//    max-of-32 tail and staggers GEMM2's L2 demand burst.
//  - everything else identical to R18: wave-private barrier-free GEMM staging via
//    global_load_lds double-buffer, chunk-XOR B swizzle, swizzled LDS A, X in LDS,
//    fixed-31 predicated prefix, fixup-in-LDS, fused D*u epilogue.
#define BB     16
#define LSEQ   1024
#define HH     256
#define PP     256
#define LC     32
#define NC     (LSEQ/LC)     // 32
#define NCHUNK (BB*NC)       // 512

// workspace byte offsets
#define OFF_W1T  0u          // [512][256] bf16: row 2p=Re(B_bar[p][.]), 2p+1=Im
#define OFF_W2T  262144u     // [256][512] bf16: row h, k=2p -> 2*C_re, 2p+1 -> -2*C_im
#define OFF_PW   524288u     // [33][256] float2: lambda_bar^t
#define OFF_CEND 655360u     // [512][256] float2 chunk-end local states (1 MB)
#define OFF_BAR  2752512u    // per-batch readiness masks: 16 x 64 B (zeroed by k_prep)

typedef __attribute__((ext_vector_type(8))) short short8;
typedef __attribute__((ext_vector_type(4))) float floatx4;
typedef unsigned long long ull;

__device__ __forceinline__ float bf2f(unsigned hs) {
    union { unsigned u; float f; } v; v.u = hs << 16; return v.f;
}
__device__ __forceinline__ unsigned short f2bs(float f) {
    __hip_bfloat16 h = __float2bfloat16(f);
    union { __hip_bfloat16 h; unsigned short s; } v; v.h = h; return v.s;
}
__device__ __forceinline__ unsigned packbf(float r, float i) {
    return (unsigned)f2bs(r) | ((unsigned)f2bs(i) << 16);
}
__device__ __forceinline__ void async16(const void* g, void* l) {
    __builtin_amdgcn_global_load_lds(
        (const __attribute__((address_space(1))) unsigned*)g,
        (__attribute__((address_space(3))) unsigned*)l, 16, 0, 0);
}
__device__ __forceinline__ float2 lam_pow(float lr, float li, float dtt) {
    float m = expf(lr * dtt);
    return make_float2(m * cosf(li * dtt), m * sinf(li * dtt));
}
__device__ __forceinline__ void cohst64(ull* p, float2 v) {
    ull b; __builtin_memcpy(&b, &v, 8);
    __hip_atomic_store(p, b, __ATOMIC_RELAXED, __HIP_MEMORY_SCOPE_AGENT);
}

// Staggered carry-ready wait. Producer side: CEND sc1 stores drained (vmcnt(0))
// before the atomicOr publishes bit c. Consumer: spin until bits 0..c-1 set.
// Chunk 0 exits immediately; average wait ~ c/32 of a batch, not max-of-32.
__device__ __forceinline__ void carrywait(char* base, int c) {
    asm volatile("s_waitcnt vmcnt(0)" ::: "memory");   // CEND at coherent point
    __syncthreads();
    if (threadIdx.x == 0) {
        const unsigned b = blockIdx.x >> 5;
        unsigned* mask = (unsigned*)(base + b * 64);
        __hip_atomic_fetch_or(mask, 1u << c, __ATOMIC_RELAXED, __HIP_MEMORY_SCOPE_AGENT);
        const unsigned need = (c == 0) ? 0u : ((1u << c) - 1u);
        if (need) {
            for (int it = 0; it < (1 << 18); ++it) {   // bounded: no hang
                if ((__hip_atomic_load(mask, __ATOMIC_RELAXED,
                                       __HIP_MEMORY_SCOPE_AGENT) & need) == need)
                    break;
                __builtin_amdgcn_s_sleep(2);
            }
        }
    }
    __syncthreads();
}

// ---------------- k_prep: W1T/PW (blocks 0..255), W2T (256..511), mask init -----
__global__ void k_prep(const float* __restrict__ Bm, const float* __restrict__ Cm,
                       const float* __restrict__ Lr, const float* __restrict__ Li,
                       const float* __restrict__ ls, char* __restrict__ ws) {
    int blk = blockIdx.x, t = threadIdx.x;
    if (blk < 256) {
        if (t < 128) {
            int p = blk;
            float lr = Lr[p], li = Li[p];
            float dt = expf(ls[p]);
            float2 lam = lam_pow(lr, li, dt);
            float den = lr * lr + li * li;
            float nr = lam.x - 1.0f, ni = lam.y;
            float cr = (nr * lr + ni * li) / den;    // (lam_bar-1)/Lambda
            float ci = (ni * lr - nr * li) / den;
            float4 bv = *(const float4*)(Bm + (size_t)p * 512 + 4 * t);
            unsigned* w1u = (unsigned*)(ws + OFF_W1T);
            w1u[(2 * p) * 128 + t]     = packbf(cr * bv.x - ci * bv.y, cr * bv.z - ci * bv.w);
            w1u[(2 * p + 1) * 128 + t] = packbf(cr * bv.y + ci * bv.x, cr * bv.w + ci * bv.z);
            if (t <= 32)
                ((float2*)(ws + OFF_PW))[t * 256 + p] = lam_pow(lr, li, dt * (float)t);
        }
        if (blk == 0)   // zero readiness-mask area (4 KB)
            ((float4*)(ws + OFF_BAR))[t] = make_float4(0.f, 0.f, 0.f, 0.f);
    } else {
        int h = blk - 256, p = t;
        float c_r = Cm[(h * PP + p) * 2 + 0];
        float c_i = Cm[(h * PP + p) * 2 + 1];
        ((unsigned*)(ws + OFF_W2T))[h * 256 + p] = packbf(2.0f * c_r, -2.0f * c_i);
    }
}

// LDS map (81920 B, 2 blocks/CU = 160 KB exactly):
//   GEMM1 : A  @0      [32 rows][512 B] bf16, k-byte XOR-swizzled by (row&7)<<4
//           B1 @16384  2 bufs x 32768 B ([8 waves][64 rows][64 B], chunk-swizzled)
//   later : X  @0      [32][520] bf16 (33280 B)
//           carrs @33280 [256] float2 (2 KB)
//           B2 @35328  2 bufs x 16384 B ([8 waves][32 rows][64 B], chunk-swizzled)
#define XSTRS 520
#define XSTRD 260
#define CARR_OFF 33280
#define B1_OFF  16384
#define B2_OFF  35328

__global__ __launch_bounds__(512, 4) void k_main(
        const float* __restrict__ u, const float* __restrict__ Lr,
        const float* __restrict__ Li, const float* __restrict__ ls,
        const float* __restrict__ D, float* __restrict__ out,
        char* __restrict__ ws) {
    extern __shared__ char smem[];
    const int tid = threadIdx.x, bc = blockIdx.x;
    const int wave = tid >> 6, lane = tid & 63;
    const int q = lane >> 4, rr = lane & 15;
    const int m0 = bc * LC;
    const int fs = (lane >> 3) & 3;          // staging swizzle = (R>>1)&3 for own slot
    const int fr = (rr >> 1) & 3;            // read swizzle    = (R>>1)&3 for own row

    // ---- GEMM1 panel-0 DMA first (wave-private slice; flies under u-load/pack) --
    {
        const char* W1 = (const char*)(ws + OFF_W1T);
        char* dst = smem + B1_OFF + wave * 4096;
        #pragma unroll
        for (int i = 0; i < 4; ++i) {
            int n = i * 64 + lane;                       // slot in own 4 KB slice
            int R = wave * 64 + (n >> 2);                // global B-row
            async16(W1 + (size_t)R * 512 + (((n & 3) ^ fs) << 4), dst + n * 16);
        }
    }

    // ---- u tile preload + pack -> bf16 into swizzled LDS A ----------------------
    const int arow = tid >> 4, acol = (tid & 15) * 16;   // 16 f32 elems/thread
    {
        float4 uv[4];
        const float* up = u + (size_t)(m0 + arow) * 256 + acol;
        #pragma unroll
        for (int i = 0; i < 4; ++i) uv[i] = *(const float4*)(up + 4 * i);
        unsigned pk[8];
        #pragma unroll
        for (int i = 0; i < 4; ++i) {
            pk[2 * i]     = packbf(uv[i].x, uv[i].y);
            pk[2 * i + 1] = packbf(uv[i].z, uv[i].w);
        }
        const int kb = acol * 2;                   // k-byte base (32 B/thread)
        const int msk = (arow & 7) << 4;
        char* A = smem;
        *(uint4*)(A + arow * 512 + (kb ^ msk))        = make_uint4(pk[0], pk[1], pk[2], pk[3]);
        *(uint4*)(A + arow * 512 + ((kb + 16) ^ msk)) = make_uint4(pk[4], pk[5], pk[6], pk[7]);
    }
    __syncthreads();                           // A visible to all waves

    // ---------------- GEMM1 (BM=32, BN=512, K=256), 8 panels BK=32 ---------------
    // Barrier-free: wave reads only its own staged slice.
    {
        const char* W1 = (const char*)(ws + OFF_W1T);
        const char* A = smem;
        const int amask = (rr & 7) << 4;
        floatx4 acc[2][4];
        #pragma unroll
        for (int i = 0; i < 2; ++i)
            #pragma unroll
            for (int j = 0; j < 4; ++j) acc[i][j] = (floatx4)0.0f;

        for (int t = 0; t < 8; ++t) {
            asm volatile("s_waitcnt vmcnt(0)" ::: "memory");   // own panel-t landed
            if (t < 7) {    // issue own slice of panel t+1 under this panel's MFMAs
                char* dst = smem + B1_OFF + ((t + 1) & 1) * 32768 + wave * 4096;
                const char* src = W1 + (t + 1) * 64;
                #pragma unroll
                for (int i = 0; i < 4; ++i) {
                    int n = i * 64 + lane;
                    int R = wave * 64 + (n >> 2);
                    async16(src + (size_t)R * 512 + (((n & 3) ^ fs) << 4), dst + n * 16);
                }
            }
            const char* bb = smem + B1_OFF + (t & 1) * 32768 + wave * 4096;
            const int kbA = t * 64 + q * 16;
            short8 a0 = *(const short8*)(A + rr * 512 + (kbA ^ amask));
            short8 a1 = *(const short8*)(A + (16 + rr) * 512 + (kbA ^ amask));
            #pragma unroll
            for (int j = 0; j < 4; ++j) {
                short8 b = *(const short8*)(bb + (j * 16 + rr) * 64 + ((q ^ fr) << 4));
                acc[0][j] = __builtin_amdgcn_mfma_f32_16x16x32_bf16(a0, b, acc[0][j], 0, 0, 0);
                acc[1][j] = __builtin_amdgcn_mfma_f32_16x16x32_bf16(a1, b, acc[1][j], 0, 0, 0);
            }
        }
        __syncthreads();                       // all waves done with A/B1
        // dump Bu tile (32 x 512) into padded LDS X (overwrites A + B1 head)
        unsigned short* X = (unsigned short*)smem;
        #pragma unroll
        for (int i = 0; i < 2; ++i)
            #pragma unroll
            for (int j = 0; j < 4; ++j)
                #pragma unroll
                for (int r0 = 0; r0 < 4; ++r0)
                    X[(i * 16 + q * 4 + r0) * XSTRS + wave * 64 + j * 16 + rr] =
                        f2bs(acc[i][j][r0]);
        __syncthreads();
    }

    // ---------------- local scan (waves 0-3) || GEMM2 panel-0 prestage (4-7) -----
    if (tid < 256) {
        const int pq = tid;
        const float2 lam = lam_pow(Lr[pq], Li[pq], expf(ls[pq]));
        unsigned* X32 = (unsigned*)smem;
        float xr = 0.0f, xi = 0.0f;
        #pragma unroll
        for (int j = 0; j < LC; ++j) {
            unsigned cv = X32[j * XSTRD + pq];
            float br = bf2f(cv & 0xffffu), bi = bf2f(cv >> 16);
            float nr = fmaf(lam.x, xr, fmaf(-lam.y, xi, br));
            float ni = fmaf(lam.x, xi, fmaf(lam.y, xr, bi));
            xr = nr; xi = ni;
            X32[j * XSTRD + pq] = packbf(xr, xi);   // x_local in place
        }
        cohst64((ull*)(ws + OFF_CEND) + (size_t)bc * 256 + pq, make_float2(xr, xi));
    } else {
        // prestage FULL GEMM2 panel 0 (all waves' slices) while the scan runs
        const char* W2 = (const char*)(ws + OFF_W2T);
        char* B2 = smem + B2_OFF;
        const int t4 = tid - 256;
        const int f0 = (t4 >> 3) & 3;
        #pragma unroll
        for (int i = 0; i < 4; ++i) {
            int c = i * 256 + t4;                  // linear slot 0..1023
            int R = c >> 2;                        // global B-row 0..255
            async16(W2 + (size_t)R * 1024 + (((c & 3) ^ f0) << 4), B2 + c * 16);
        }
    }
    carrywait(ws + OFF_BAR, bc & (NC - 1));    // wait only for chunks 0..c-1

    // ---------------- per-block carry via fixed-31 predicated prefix -------------
    {
        float2* carrs = (float2*)(smem + CARR_OFF);
        if (tid < 256) {
            const int p = tid;
            const int c = bc & (NC - 1);
            const int b0 = bc & ~(NC - 1);
            const float2* cend = (const float2*)(ws + OFF_CEND);
            const float2 g = lam_pow(Lr[p], Li[p], expf(ls[p]) * (float)LC);
            float sr = 0.0f, si = 0.0f;
            float gpr = 1.0f, gpi = 0.0f;
            #pragma unroll
            for (int k = 0; k < NC - 1; ++k) {
                int idx = c - 1 - k; idx = idx < 0 ? 0 : idx;
                float2 e = cend[(size_t)(b0 + idx) * 256 + p];
                float er = (k < c) ? e.x : 0.0f;
                float ei = (k < c) ? e.y : 0.0f;
                sr = fmaf(gpr, er, fmaf(-gpi, ei, sr));
                si = fmaf(gpr, ei, fmaf(gpi, er, si));
                float t2 = gpr * g.x - gpi * g.y;
                gpi = gpr * g.y + gpi * g.x; gpr = t2;
            }
            carrs[p] = make_float2(sr, si);
        }
        __syncthreads();
    }

    // ---------------- fixup X in place -------------------------------------------
    {
        float2* carrs = (float2*)(smem + CARR_OFF);
        unsigned* X32 = (unsigned*)smem;
        const float2* pw = (const float2*)(ws + OFF_PW);
        const int frow = tid >> 4, fcol = tid & 15;
        const float2* pwr = pw + (size_t)(frow + 1) * 256;
        #pragma unroll 4
        for (int e = 0; e < 16; ++e) {
            int p = fcol + e * 16;
            unsigned cv = X32[frow * XSTRD + p];
            float2 pwv = pwr[p];
            float2 cav = carrs[p];
            float fr2 = pwv.x * cav.x - pwv.y * cav.y;
            float fi2 = pwv.x * cav.y + pwv.y * cav.x;
            X32[frow * XSTRD + p] =
                packbf(bf2f(cv & 0xffffu) + fr2, bf2f(cv >> 16) + fi2);
        }
        __syncthreads();
    }

    // ---------------- GEMM2 (BM=32, BN=256, K=512), 16 panels BK=32 --------------
    // Barrier-free: wave-private slices; panel 0 was prestaged during the scan.
    {
        const char* W2 = (const char*)(ws + OFF_W2T);
        const char* Xb = (const char*)smem;
        floatx4 acc[2][2];
        #pragma unroll
        for (int i = 0; i < 2; ++i)
            #pragma unroll
            for (int j = 0; j < 2; ++j) acc[i][j] = (floatx4)0.0f;

        for (int t = 0; t < 16; ++t) {
            asm volatile("s_waitcnt vmcnt(0)" ::: "memory");   // panel t landed
            if (t < 15) {   // issue own slice of panel t+1
                char* dst = smem + B2_OFF + ((t + 1) & 1) * 16384 + wave * 2048;
                const char* src = W2 + (t + 1) * 64;
                #pragma unroll
                for (int i = 0; i < 2; ++i) {
                    int n = i * 64 + lane;
                    int R = wave * 32 + (n >> 2);
                    async16(src + (size_t)R * 1024 + (((n & 3) ^ fs) << 4), dst + n * 16);
                }
            }
            const char* bbuf = smem + B2_OFF + (t & 1) * 16384 + wave * 2048;
            const int kbA = t * 64 + q * 16;
            short8 a0 = *(const short8*)(Xb + rr * (XSTRS * 2) + kbA);
            short8 a1 = *(const short8*)(Xb + (16 + rr) * (XSTRS * 2) + kbA);
            #pragma unroll
            for (int j = 0; j < 2; ++j) {
                short8 b = *(const short8*)(bbuf + (j * 16 + rr) * 64 + ((q ^ fr) << 4));
                acc[0][j] = __builtin_amdgcn_mfma_f32_16x16x32_bf16(a0, b, acc[0][j], 0, 0, 0);
                acc[1][j] = __builtin_amdgcn_mfma_f32_16x16x32_bf16(a1, b, acc[1][j], 0, 0, 0);
            }
        }

        #pragma unroll
        for (int i = 0; i < 2; ++i) {
            int mbase = m0 + i * 16 + q * 4;
            #pragma unroll
            for (int j = 0; j < 2; ++j) {
                int col = wave * 32 + j * 16 + rr;
                #pragma unroll
                for (int r0 = 0; r0 < 4; ++r0) {
                    int rw = mbase + r0;
                    size_t gi = (size_t)rw * 256 + col;
                    out[gi] = acc[i][j][r0] + D[col] * u[gi];
                }
            }
        }
    }
}

extern "C" void kernel_launch(void* const* d_in, const int* in_sizes, int n_in,
                              void* d_out, int out_size, void* d_ws, size_t ws_size,
                              hipStream_t stream) {
    const float* u  = (const float*)d_in[0];
    const float* Lr = (const float*)d_in[1];
    const float* Li = (const float*)d_in[2];
    const float* Bm = (const float*)d_in[3];
    const float* Cm = (const float*)d_in[4];
    const float* D  = (const float*)d_in[5];
    const float* ls = (const float*)d_in[6];
    float* out = (float*)d_out;
    char* ws = (char*)d_ws;

    k_prep<<<512, 256, 0, stream>>>(Bm, Cm, Lr, Li, ls, ws);
    k_main<<<NCHUNK, 512, 81920, stream>>>(u, Lr, Li, ls, D, out, ws);
}

// Round 11
// 104.120 us; speedup vs baseline: 1.1299x; 1.0398x over previous
//
#include <hip/hip_runtime.h>
#include <hip/hip_bf16.h>
#include <math.h>

// S5 SSM layer. B_SZ=16, L=1024, H=256, P=256.
// R21 = R18 (batchbar, best 104.0us) + depth-2 GEMM pipelines:
//  - counted s_waitcnt vmcnt(4)/(2) leaves panel t+1's loads in flight while
//    waiting panel t (m135 in-order-return semantics); panel t+2 issued right
//    after panel-t LDS reads complete (lgkmcnt(0)+sched_barrier) -> each panel
//    gets ~2 iterations of load window instead of ~1 compute.
//  - GEMM2 panels 0 AND 1 prestaged by waves 4-7 during the scan.
//  - everything else identical to R18 (wave-private slices, chunk-XOR B swizzle,
//    swizzled LDS A, X in LDS, fixed-31 predicated prefix, fused D*u epilogue).
#define BB     16
#define LSEQ   1024
#define HH     256
#define PP     256
#define LC     32
#define NC     (LSEQ/LC)     // 32
#define NCHUNK (BB*NC)       // 512

// workspace byte offsets
#define OFF_W1T  0u          // [512][256] bf16: row 2p=Re(B_bar[p][.]), 2p+1=Im
#define OFF_W2T  262144u     // [256][512] bf16: row h, k=2p -> 2*C_re, 2p+1 -> -2*C_im
#define OFF_PW   524288u     // [33][256] float2: lambda_bar^t
#define OFF_CEND 655360u     // [512][256] float2 chunk-end local states (1 MB)
#define OFF_BAR  2752512u    // batch-barrier area (zeroed by k_prep block 0)

typedef __attribute__((ext_vector_type(8))) short short8;
typedef __attribute__((ext_vector_type(4))) float floatx4;
typedef unsigned long long ull;

__device__ __forceinline__ float bf2f(unsigned hs) {
    union { unsigned u; float f; } v; v.u = hs << 16; return v.f;
}
__device__ __forceinline__ unsigned short f2bs(float f) {
    __hip_bfloat16 h = __float2bfloat16(f);
    union { __hip_bfloat16 h; unsigned short s; } v; v.h = h; return v.s;
}
__device__ __forceinline__ unsigned packbf(float r, float i) {
    return (unsigned)f2bs(r) | ((unsigned)f2bs(i) << 16);
}
__device__ __forceinline__ void async16(const void* g, void* l) {
    __builtin_amdgcn_global_load_lds(
        (const __attribute__((address_space(1))) unsigned*)g,
        (__attribute__((address_space(3))) unsigned*)l, 16, 0, 0);
}
__device__ __forceinline__ float2 lam_pow(float lr, float li, float dtt) {
    float m = expf(lr * dtt);
    return make_float2(m * cosf(li * dtt), m * sinf(li * dtt));
}
__device__ __forceinline__ void cohst64(ull* p, float2 v) {
    ull b; __builtin_memcpy(&b, &v, 8);
    __hip_atomic_store(p, b, __ATOMIC_RELAXED, __HIP_MEMORY_SCOPE_AGENT);
}

// Batch-scope barrier: 32 blocks of one batch (bc>>5). No cache fences —
// CEND uses sc1 stores (coherent at L3); vmcnt(0) drains them pre-arrival.
__device__ __forceinline__ void batchbar(char* base) {
    asm volatile("s_waitcnt vmcnt(0)" ::: "memory");
    __syncthreads();
    if (threadIdx.x == 0) {
        const unsigned b = blockIdx.x >> 5;
        unsigned* cnt  = (unsigned*)(base + b * 64);
        unsigned* flag = (unsigned*)(base + 2048 + b * 64);
        if (__hip_atomic_fetch_add(cnt, 1u, __ATOMIC_RELAXED,
                                   __HIP_MEMORY_SCOPE_AGENT) == 31u) {
            __hip_atomic_store(flag, 1u, __ATOMIC_RELAXED, __HIP_MEMORY_SCOPE_AGENT);
        } else {
            for (int it = 0; it < (1 << 18); ++it) {   // bounded: no hang
                if (__hip_atomic_load(flag, __ATOMIC_RELAXED, __HIP_MEMORY_SCOPE_AGENT))
                    break;
                __builtin_amdgcn_s_sleep(2);
            }
        }
    }
    __syncthreads();
}

// ---------------- k_prep: W1T/PW (blocks 0..255), W2T (256..511), bar init ------
__global__ void k_prep(const float* __restrict__ Bm, const float* __restrict__ Cm,
                       const float* __restrict__ Lr, const float* __restrict__ Li,
                       const float* __restrict__ ls, char* __restrict__ ws) {
    int blk = blockIdx.x, t = threadIdx.x;
    if (blk < 256) {
        if (t < 128) {
            int p = blk;
            float lr = Lr[p], li = Li[p];
            float dt = expf(ls[p]);
            float2 lam = lam_pow(lr, li, dt);
            float den = lr * lr + li * li;
            float nr = lam.x - 1.0f, ni = lam.y;
            float cr = (nr * lr + ni * li) / den;    // (lam_bar-1)/Lambda
            float ci = (ni * lr - nr * li) / den;
            float4 bv = *(const float4*)(Bm + (size_t)p * 512 + 4 * t);
            unsigned* w1u = (unsigned*)(ws + OFF_W1T);
            w1u[(2 * p) * 128 + t]     = packbf(cr * bv.x - ci * bv.y, cr * bv.z - ci * bv.w);
            w1u[(2 * p + 1) * 128 + t] = packbf(cr * bv.y + ci * bv.x, cr * bv.w + ci * bv.z);
            if (t <= 32)
                ((float2*)(ws + OFF_PW))[t * 256 + p] = lam_pow(lr, li, dt * (float)t);
        }
        if (blk == 0)   // zero batch-barrier area (4 KB)
            ((float4*)(ws + OFF_BAR))[t] = make_float4(0.f, 0.f, 0.f, 0.f);
    } else {
        int h = blk - 256, p = t;
        float c_r = Cm[(h * PP + p) * 2 + 0];
        float c_i = Cm[(h * PP + p) * 2 + 1];
        ((unsigned*)(ws + OFF_W2T))[h * 256 + p] = packbf(2.0f * c_r, -2.0f * c_i);
    }
}

// LDS map (81920 B, 2 blocks/CU = 160 KB exactly):
//   GEMM1 : A  @0      [32 rows][512 B] bf16, k-byte XOR-swizzled by (row&7)<<4
//           B1 @16384  2 bufs x 32768 B ([8 waves][64 rows][64 B], chunk-swizzled)
//   later : X  @0      [32][520] bf16 (33280 B)
//           carrs @33280 [256] float2 (2 KB)
//           B2 @35328  2 bufs x 16384 B ([8 waves][32 rows][64 B], chunk-swizzled)
#define XSTRS 520
#define XSTRD 260
#define CARR_OFF 33280
#define B1_OFF  16384
#define B2_OFF  35328

__global__ __launch_bounds__(512, 4) void k_main(
        const float* __restrict__ u, const float* __restrict__ Lr,
        const float* __restrict__ Li, const float* __restrict__ ls,
        const float* __restrict__ D, float* __restrict__ out,
        char* __restrict__ ws) {
    extern __shared__ char smem[];
    const int tid = threadIdx.x, bc = blockIdx.x;
    const int wave = tid >> 6, lane = tid & 63;
    const int q = lane >> 4, rr = lane & 15;
    const int m0 = bc * LC;
    const int fs = (lane >> 3) & 3;          // staging swizzle = (R>>1)&3 for own slot
    const int fr = (rr >> 1) & 3;            // read swizzle    = (R>>1)&3 for own row

    // ---- GEMM1 panel-0 DMA first (wave-private slice; flies under u-load/pack) --
    const char* W1 = (const char*)(ws + OFF_W1T);
    {
        char* dst = smem + B1_OFF + wave * 4096;
        #pragma unroll
        for (int i = 0; i < 4; ++i) {
            int n = i * 64 + lane;                       // slot in own 4 KB slice
            int R = wave * 64 + (n >> 2);                // global B-row
            async16(W1 + (size_t)R * 512 + (((n & 3) ^ fs) << 4), dst + n * 16);
        }
    }

    // ---- u tile preload + pack -> bf16 into swizzled LDS A ----------------------
    const int arow = tid >> 4, acol = (tid & 15) * 16;   // 16 f32 elems/thread
    {
        float4 uv[4];
        const float* up = u + (size_t)(m0 + arow) * 256 + acol;
        #pragma unroll
        for (int i = 0; i < 4; ++i) uv[i] = *(const float4*)(up + 4 * i);
        unsigned pk[8];
        #pragma unroll
        for (int i = 0; i < 4; ++i) {
            pk[2 * i]     = packbf(uv[i].x, uv[i].y);
            pk[2 * i + 1] = packbf(uv[i].z, uv[i].w);
        }
        const int kb = acol * 2;                   // k-byte base (32 B/thread)
        const int msk = (arow & 7) << 4;
        char* A = smem;
        *(uint4*)(A + arow * 512 + (kb ^ msk))        = make_uint4(pk[0], pk[1], pk[2], pk[3]);
        *(uint4*)(A + arow * 512 + ((kb + 16) ^ msk)) = make_uint4(pk[4], pk[5], pk[6], pk[7]);
    }

    // ---- GEMM1 panel-1 DMA (own slice; target buffer is wave-private) -----------
    {
        char* dst = smem + B1_OFF + 32768 + wave * 4096;
        const char* src = W1 + 64;
        #pragma unroll
        for (int i = 0; i < 4; ++i) {
            int n = i * 64 + lane;
            int R = wave * 64 + (n >> 2);
            async16(src + (size_t)R * 512 + (((n & 3) ^ fs) << 4), dst + n * 16);
        }
    }
    __syncthreads();                           // A visible to all waves

    // ---------------- GEMM1 (BM=32, BN=512, K=256), 8 panels BK=32 ---------------
    // Depth-2 pipeline: wait panel t with vmcnt(4) (t+1 in flight); after panel-t
    // LDS reads complete, issue panel t+2 into the just-freed buffer.
    {
        const char* A = smem;
        const int amask = (rr & 7) << 4;
        floatx4 acc[2][4];
        #pragma unroll
        for (int i = 0; i < 2; ++i)
            #pragma unroll
            for (int j = 0; j < 4; ++j) acc[i][j] = (floatx4)0.0f;

        #pragma unroll
        for (int t = 0; t < 8; ++t) {
            if (t < 7) { asm volatile("s_waitcnt vmcnt(4)" ::: "memory"); }
            else       { asm volatile("s_waitcnt vmcnt(0)" ::: "memory"); }
            const char* bb = smem + B1_OFF + (t & 1) * 32768 + wave * 4096;
            const int kbA = t * 64 + q * 16;
            short8 a0 = *(const short8*)(A + rr * 512 + (kbA ^ amask));
            short8 a1 = *(const short8*)(A + (16 + rr) * 512 + (kbA ^ amask));
            short8 bfr[4];
            #pragma unroll
            for (int j = 0; j < 4; ++j)
                bfr[j] = *(const short8*)(bb + (j * 16 + rr) * 64 + ((q ^ fr) << 4));
            asm volatile("s_waitcnt lgkmcnt(0)" ::: "memory");   // reads in regs
            __builtin_amdgcn_sched_barrier(0);
            if (t < 6) {    // issue panel t+2 into buf (t&1), just freed
                char* dst = smem + B1_OFF + (t & 1) * 32768 + wave * 4096;
                const char* src = W1 + (t + 2) * 64;
                #pragma unroll
                for (int i = 0; i < 4; ++i) {
                    int n = i * 64 + lane;
                    int R = wave * 64 + (n >> 2);
                    async16(src + (size_t)R * 512 + (((n & 3) ^ fs) << 4), dst + n * 16);
                }
            }
            #pragma unroll
            for (int j = 0; j < 4; ++j) {
                acc[0][j] = __builtin_amdgcn_mfma_f32_16x16x32_bf16(a0, bfr[j], acc[0][j], 0, 0, 0);
                acc[1][j] = __builtin_amdgcn_mfma_f32_16x16x32_bf16(a1, bfr[j], acc[1][j], 0, 0, 0);
            }
        }
        __syncthreads();                       // all waves done with A/B1
        // dump Bu tile (32 x 512) into padded LDS X (overwrites A + B1 head)
        unsigned short* X = (unsigned short*)smem;
        #pragma unroll
        for (int i = 0; i < 2; ++i)
            #pragma unroll
            for (int j = 0; j < 4; ++j)
                #pragma unroll
                for (int r0 = 0; r0 < 4; ++r0)
                    X[(i * 16 + q * 4 + r0) * XSTRS + wave * 64 + j * 16 + rr] =
                        f2bs(acc[i][j][r0]);
        __syncthreads();
    }

    // ---------------- local scan (waves 0-3) || GEMM2 panels 0+1 prestage (4-7) --
    if (tid < 256) {
        const int pq = tid;
        const float2 lam = lam_pow(Lr[pq], Li[pq], expf(ls[pq]));
        unsigned* X32 = (unsigned*)smem;
        float xr = 0.0f, xi = 0.0f;
        #pragma unroll
        for (int j = 0; j < LC; ++j) {
            unsigned cv = X32[j * XSTRD + pq];
            float br = bf2f(cv & 0xffffu), bi = bf2f(cv >> 16);
            float nr = fmaf(lam.x, xr, fmaf(-lam.y, xi, br));
            float ni = fmaf(lam.x, xi, fmaf(lam.y, xr, bi));
            xr = nr; xi = ni;
            X32[j * XSTRD + pq] = packbf(xr, xi);   // x_local in place
        }
        cohst64((ull*)(ws + OFF_CEND) + (size_t)bc * 256 + pq, make_float2(xr, xi));
    } else {
        // prestage FULL GEMM2 panels 0 and 1 (all waves' slices) during the scan
        const char* W2 = (const char*)(ws + OFF_W2T);
        char* B2 = smem + B2_OFF;
        const int t4 = tid - 256;
        const int f0 = (t4 >> 3) & 3;
        #pragma unroll
        for (int pan = 0; pan < 2; ++pan) {
            #pragma unroll
            for (int i = 0; i < 4; ++i) {
                int c = i * 256 + t4;              // linear slot 0..1023
                int R = c >> 2;                    // global B-row 0..255
                async16(W2 + (size_t)R * 1024 + pan * 64 + (((c & 3) ^ f0) << 4),
                        B2 + pan * 16384 + c * 16);
            }
        }
    }
    batchbar(ws + OFF_BAR);        // this batch's CEND coherent; panels 0,1 visible

    // ---------------- per-block carry via fixed-31 predicated prefix -------------
    {
        float2* carrs = (float2*)(smem + CARR_OFF);
        if (tid < 256) {
            const int p = tid;
            const int c = bc & (NC - 1);
            const int b0 = bc & ~(NC - 1);
            const float2* cend = (const float2*)(ws + OFF_CEND);
            const float2 g = lam_pow(Lr[p], Li[p], expf(ls[p]) * (float)LC);
            float sr = 0.0f, si = 0.0f;
            float gpr = 1.0f, gpi = 0.0f;
            #pragma unroll
            for (int k = 0; k < NC - 1; ++k) {
                int idx = c - 1 - k; idx = idx < 0 ? 0 : idx;
                float2 e = cend[(size_t)(b0 + idx) * 256 + p];
                float er = (k < c) ? e.x : 0.0f;
                float ei = (k < c) ? e.y : 0.0f;
                sr = fmaf(gpr, er, fmaf(-gpi, ei, sr));
                si = fmaf(gpr, ei, fmaf(gpi, er, si));
                float t2 = gpr * g.x - gpi * g.y;
                gpi = gpr * g.y + gpi * g.x; gpr = t2;
            }
            carrs[p] = make_float2(sr, si);
        }
        __syncthreads();
    }

    // ---------------- fixup X in place -------------------------------------------
    {
        float2* carrs = (float2*)(smem + CARR_OFF);
        unsigned* X32 = (unsigned*)smem;
        const float2* pw = (const float2*)(ws + OFF_PW);
        const int frow = tid >> 4, fcol = tid & 15;
        const float2* pwr = pw + (size_t)(frow + 1) * 256;
        #pragma unroll 4
        for (int e = 0; e < 16; ++e) {
            int p = fcol + e * 16;
            unsigned cv = X32[frow * XSTRD + p];
            float2 pwv = pwr[p];
            float2 cav = carrs[p];
            float fr2 = pwv.x * cav.x - pwv.y * cav.y;
            float fi2 = pwv.x * cav.y + pwv.y * cav.x;
            X32[frow * XSTRD + p] =
                packbf(bf2f(cv & 0xffffu) + fr2, bf2f(cv >> 16) + fi2);
        }
        __syncthreads();
    }

    // ---------------- GEMM2 (BM=32, BN=256, K=512), 16 panels BK=32 --------------
    // Depth-2 pipeline; panels 0,1 prestaged -> first waits are free.
    {
        const char* W2 = (const char*)(ws + OFF_W2T);
        const char* Xb = (const char*)smem;
        floatx4 acc[2][2];
        #pragma unroll
        for (int i = 0; i < 2; ++i)
            #pragma unroll
            for (int j = 0; j < 2; ++j) acc[i][j] = (floatx4)0.0f;

        #pragma unroll
        for (int t = 0; t < 16; ++t) {
            if (t < 15) { asm volatile("s_waitcnt vmcnt(2)" ::: "memory"); }
            else        { asm volatile("s_waitcnt vmcnt(0)" ::: "memory"); }
            const char* bbuf = smem + B2_OFF + (t & 1) * 16384 + wave * 2048;
            const int kbA = t * 64 + q * 16;
            short8 a0 = *(const short8*)(Xb + rr * (XSTRS * 2) + kbA);
            short8 a1 = *(const short8*)(Xb + (16 + rr) * (XSTRS * 2) + kbA);
            short8 bfr[2];
            #pragma unroll
            for (int j = 0; j < 2; ++j)
                bfr[j] = *(const short8*)(bbuf + (j * 16 + rr) * 64 + ((q ^ fr) << 4));
            asm volatile("s_waitcnt lgkmcnt(0)" ::: "memory");   // reads in regs
            __builtin_amdgcn_sched_barrier(0);
            if (t < 14) {   // issue panel t+2 into buf (t&1), just freed
                char* dst = smem + B2_OFF + (t & 1) * 16384 + wave * 2048;
                const char* src = W2 + (t + 2) * 64;
                #pragma unroll
                for (int i = 0; i < 2; ++i) {
                    int n = i * 64 + lane;
                    int R = wave * 32 + (n >> 2);
                    async16(src + (size_t)R * 1024 + (((n & 3) ^ fs) << 4), dst + n * 16);
                }
            }
            #pragma unroll
            for (int j = 0; j < 2; ++j) {
                acc[0][j] = __builtin_amdgcn_mfma_f32_16x16x32_bf16(a0, bfr[j], acc[0][j], 0, 0, 0);
                acc[1][j] = __builtin_amdgcn_mfma_f32_16x16x32_bf16(a1, bfr[j], acc[1][j], 0, 0, 0);
            }
        }

        #pragma unroll
        for (int i = 0; i < 2; ++i) {
            int mbase = m0 + i * 16 + q * 4;
            #pragma unroll
            for (int j = 0; j < 2; ++j) {
                int col = wave * 32 + j * 16 + rr;
                #pragma unroll
                for (int r0 = 0; r0 < 4; ++r0) {
                    int rw = mbase + r0;
                    size_t gi = (size_t)rw * 256 + col;
                    out[gi] = acc[i][j][r0] + D[col] * u[gi];
                }
            }
        }
    }
}

extern "C" void kernel_launch(void* const* d_in, const int* in_sizes, int n_in,
                              void* d_out, int out_size, void* d_ws, size_t ws_size,
                              hipStream_t stream) {
    const float* u  = (const float*)d_in[0];
    const float* Lr = (const float*)d_in[1];
    const float* Li = (const float*)d_in[2];
    const float* Bm = (const float*)d_in[3];
    const float* Cm = (const float*)d_in[4];
    const float* D  = (const float*)d_in[5];
    const float* ls = (const float*)d_in[6];
    float* out = (float*)d_out;
    char* ws = (char*)d_ws;

    k_prep<<<512, 256, 0, stream>>>(Bm, Cm, Lr, Li, ls, ws);
    k_main<<<NCHUNK, 512, 81920, stream>>>(u, Lr, Li, ls, D, out, ws);
}